// Round 13
// baseline (17869.962 us; speedup 1.0000x reference)
//
#include <hip/hip_runtime.h>

typedef unsigned short u16;
typedef __attribute__((ext_vector_type(8))) short s16x8;
typedef __attribute__((ext_vector_type(2))) float f32x2;
typedef __attribute__((ext_vector_type(4))) float f32x4;
typedef __attribute__((ext_vector_type(4))) unsigned int u32x4;
typedef __attribute__((ext_vector_type(4))) unsigned short u16x4;

#define RG 16  // reservoir blocks

__device__ __forceinline__ float b2f(u16 u) {
  return __uint_as_float(((unsigned int)u) << 16);
}
__device__ __forceinline__ u16 f2b(float f) {   // RNE f32 -> bf16
  unsigned int x = __float_as_uint(f);
  x += 0x7fffu + ((x >> 16) & 1u);
  return (u16)(x >> 16);
}

// ---------------- f32 -> bf16 cast, 4 elems/thread ----------------
__global__ void cast_ker(const float* __restrict__ in, u16* __restrict__ out, int n4) {
  int i = blockIdx.x * blockDim.x + threadIdx.x;
  if (i >= n4) return;
  f32x4 v = ((const f32x4*)in)[i];
  u16x4 o;
  o.x = f2b(v.x); o.y = f2b(v.y); o.z = f2b(v.z); o.w = f2b(v.w);
  ((u16x4*)out)[i] = o;
}

// ---------------- GEMM: C[M,N] = act(Abf16[M,K] @ Bbf16[N,K]^T + biasf32) ----------------
template<int ACT, int BIAS, int WF32, int WB16>
__global__ __launch_bounds__(256)
void gemm_bt(const u16* __restrict__ A, const u16* __restrict__ B,
             const float* __restrict__ bias, float* __restrict__ Cf,
             u16* __restrict__ Cb, int M, int N, int K) {
  __shared__ u16 As[128 * 40];
  __shared__ u16 Bs[128 * 40];
  const int tid  = threadIdx.x;
  const int lane = tid & 63;
  const int wave = tid >> 6;
  const int wm = wave >> 1, wn = wave & 1;
  const int bm = blockIdx.x << 7;
  const int bn = blockIdx.y << 7;
  const int sr = tid >> 2;
  const int sc = (tid & 3) << 3;

  f32x4 acc[4][4];
#pragma unroll
  for (int m = 0; m < 4; ++m)
#pragma unroll
    for (int n = 0; n < 4; ++n) acc[m][n] = f32x4{0.f, 0.f, 0.f, 0.f};

  const int row0 = (wm << 6) + (lane & 15);
  const int col0 = (wn << 6) + (lane & 15);
  const int k8   = (lane >> 4) << 3;

  for (int kt = 0; kt < K; kt += 32) {
    u32x4 a0 = *(const u32x4*)(A + (size_t)(bm + sr) * K + kt + sc);
    u32x4 a1 = *(const u32x4*)(A + (size_t)(bm + sr + 64) * K + kt + sc);
    u32x4 b0 = *(const u32x4*)(B + (size_t)(bn + sr) * K + kt + sc);
    u32x4 b1 = *(const u32x4*)(B + (size_t)(bn + sr + 64) * K + kt + sc);
    __syncthreads();
    *(u32x4*)(As + sr * 40 + sc) = a0;
    *(u32x4*)(As + (sr + 64) * 40 + sc) = a1;
    *(u32x4*)(Bs + sr * 40 + sc) = b0;
    *(u32x4*)(Bs + (sr + 64) * 40 + sc) = b1;
    __syncthreads();

    s16x8 af[4], bfr[4];
#pragma unroll
    for (int m = 0; m < 4; ++m)
      af[m] = *(const s16x8*)(As + (row0 + m * 16) * 40 + k8);
#pragma unroll
    for (int n = 0; n < 4; ++n)
      bfr[n] = *(const s16x8*)(Bs + (col0 + n * 16) * 40 + k8);
#pragma unroll
    for (int m = 0; m < 4; ++m)
#pragma unroll
      for (int n = 0; n < 4; ++n)
        acc[m][n] = __builtin_amdgcn_mfma_f32_16x16x32_bf16(af[m], bfr[n], acc[m][n], 0, 0, 0);
  }

  const int crow = (wm << 6) + ((lane >> 4) << 2);
  const int ccol = (wn << 6) + (lane & 15);
#pragma unroll
  for (int m = 0; m < 4; ++m) {
#pragma unroll
    for (int n = 0; n < 4; ++n) {
      const int c = bn + ccol + n * 16;
      const float bv = BIAS ? bias[c] : 0.f;
#pragma unroll
      for (int i = 0; i < 4; ++i) {
        const int r = bm + crow + m * 16 + i;
        float v = acc[m][n][i] + bv;
        if (ACT) v = fmaxf(v, 0.f);
        if (WF32) Cf[(size_t)r * N + c] = v;
        if (WB16) Cb[(size_t)r * N + c] = f2b(v);
      }
    }
  }
}

// ---------------- split-precision GEMM: C[M,N] = Af32[M,K] @ Bf32[N,K]^T ----------------
__global__ __launch_bounds__(256)
void gemm_split(const float* __restrict__ A, const float* __restrict__ B,
                float* __restrict__ C, int M, int N, int K) {
  __shared__ u16 Ah[128 * 40];
  __shared__ u16 Al[128 * 40];
  __shared__ u16 Bh[128 * 40];
  __shared__ u16 Bl[128 * 40];
  const int tid  = threadIdx.x;
  const int lane = tid & 63;
  const int wave = tid >> 6;
  const int wm = wave >> 1, wn = wave & 1;
  const int bm = blockIdx.x << 7;
  const int bn = blockIdx.y << 7;
  const int sr = tid >> 2;
  const int sc = (tid & 3) << 3;

  f32x4 acc[4][4];
#pragma unroll
  for (int m = 0; m < 4; ++m)
#pragma unroll
    for (int n = 0; n < 4; ++n) acc[m][n] = f32x4{0.f, 0.f, 0.f, 0.f};

  const int row0 = (wm << 6) + (lane & 15);
  const int col0 = (wn << 6) + (lane & 15);
  const int k8   = (lane >> 4) << 3;

  for (int kt = 0; kt < K; kt += 32) {
    f32x4 a0 = *(const f32x4*)(A + (size_t)(bm + sr) * K + kt + sc);
    f32x4 a1 = *(const f32x4*)(A + (size_t)(bm + sr) * K + kt + sc + 4);
    f32x4 a2 = *(const f32x4*)(A + (size_t)(bm + sr + 64) * K + kt + sc);
    f32x4 a3 = *(const f32x4*)(A + (size_t)(bm + sr + 64) * K + kt + sc + 4);
    f32x4 b0 = *(const f32x4*)(B + (size_t)(bn + sr) * K + kt + sc);
    f32x4 b1 = *(const f32x4*)(B + (size_t)(bn + sr) * K + kt + sc + 4);
    f32x4 b2 = *(const f32x4*)(B + (size_t)(bn + sr + 64) * K + kt + sc);
    f32x4 b3 = *(const f32x4*)(B + (size_t)(bn + sr + 64) * K + kt + sc + 4);
    __syncthreads();
#pragma unroll
    for (int j = 0; j < 4; ++j) {
      float av, rs; u16 h;
      av = a0[j]; h = f2b(av); rs = av - b2f(h);
      Ah[sr * 40 + sc + j] = h;            Al[sr * 40 + sc + j] = f2b(rs);
      av = a1[j]; h = f2b(av); rs = av - b2f(h);
      Ah[sr * 40 + sc + 4 + j] = h;        Al[sr * 40 + sc + 4 + j] = f2b(rs);
      av = a2[j]; h = f2b(av); rs = av - b2f(h);
      Ah[(sr + 64) * 40 + sc + j] = h;     Al[(sr + 64) * 40 + sc + j] = f2b(rs);
      av = a3[j]; h = f2b(av); rs = av - b2f(h);
      Ah[(sr + 64) * 40 + sc + 4 + j] = h; Al[(sr + 64) * 40 + sc + 4 + j] = f2b(rs);
      av = b0[j]; h = f2b(av); rs = av - b2f(h);
      Bh[sr * 40 + sc + j] = h;            Bl[sr * 40 + sc + j] = f2b(rs);
      av = b1[j]; h = f2b(av); rs = av - b2f(h);
      Bh[sr * 40 + sc + 4 + j] = h;        Bl[sr * 40 + sc + 4 + j] = f2b(rs);
      av = b2[j]; h = f2b(av); rs = av - b2f(h);
      Bh[(sr + 64) * 40 + sc + j] = h;     Bl[(sr + 64) * 40 + sc + j] = f2b(rs);
      av = b3[j]; h = f2b(av); rs = av - b2f(h);
      Bh[(sr + 64) * 40 + sc + 4 + j] = h; Bl[(sr + 64) * 40 + sc + 4 + j] = f2b(rs);
    }
    __syncthreads();

    s16x8 afh[4], afl[4], bfh[4], bfl[4];
#pragma unroll
    for (int m = 0; m < 4; ++m) {
      afh[m] = *(const s16x8*)(Ah + (row0 + m * 16) * 40 + k8);
      afl[m] = *(const s16x8*)(Al + (row0 + m * 16) * 40 + k8);
    }
#pragma unroll
    for (int n = 0; n < 4; ++n) {
      bfh[n] = *(const s16x8*)(Bh + (col0 + n * 16) * 40 + k8);
      bfl[n] = *(const s16x8*)(Bl + (col0 + n * 16) * 40 + k8);
    }
#pragma unroll
    for (int m = 0; m < 4; ++m)
#pragma unroll
      for (int n = 0; n < 4; ++n) {
        acc[m][n] = __builtin_amdgcn_mfma_f32_16x16x32_bf16(afh[m], bfh[n], acc[m][n], 0, 0, 0);
        acc[m][n] = __builtin_amdgcn_mfma_f32_16x16x32_bf16(afh[m], bfl[n], acc[m][n], 0, 0, 0);
        acc[m][n] = __builtin_amdgcn_mfma_f32_16x16x32_bf16(afl[m], bfh[n], acc[m][n], 0, 0, 0);
      }
  }

  const int crow = (wm << 6) + ((lane >> 4) << 2);
  const int ccol = (wn << 6) + (lane & 15);
#pragma unroll
  for (int m = 0; m < 4; ++m)
#pragma unroll
    for (int n = 0; n < 4; ++n) {
      const int c = bn + ccol + n * 16;
#pragma unroll
      for (int i = 0; i < 4; ++i)
        C[(size_t)(bm + crow + m * 16 + i) * N + c] = acc[m][n][i];
    }
}

// ---------------- z = mu + eps * exp(0.5*log_var), f32, 4 elems/thread ----------------
__global__ void z_ker(const float* __restrict__ mu, const float* __restrict__ lv,
                      const float* __restrict__ eps, float* __restrict__ z,
                      u16* __restrict__ zb, int n4) {
  int i = blockIdx.x * blockDim.x + threadIdx.x;
  if (i >= n4) return;
  f32x4 m4 = ((const f32x4*)mu)[i];
  f32x4 l4 = ((const f32x4*)lv)[i];
  f32x4 e4 = ((const f32x4*)eps)[i];
  f32x4 o;
  o.x = m4.x + e4.x * __expf(0.5f * l4.x);
  o.y = m4.y + e4.y * __expf(0.5f * l4.y);
  o.z = m4.z + e4.z * __expf(0.5f * l4.z);
  o.w = m4.w + e4.w * __expf(0.5f * l4.w);
  ((f32x4*)z)[i] = o;
  u16x4 ob; ob.x = f2b(o.x); ob.y = f2b(o.y); ob.z = f2b(o.z); ob.w = f2b(o.w);
  ((u16x4*)zb)[i] = ob;
}

// ---------------- reservoir scan: state = tanh(Wrec @ state + u[t]) ----------------
// r6/r12 structure + TWO-DEEP PIPELINED POLL, fully inside one asm block:
// slots A(2x dwordx2) and B(2x dwordx2) alternate; vmcnt(2) always completes
// the OLDEST slot, which is the one tested (invariant holds across reissues).
// Ready test: v_cmp_ne_u64 on each pair (values in (1,3); producer's 64B-aligned
// single-instruction store makes the line appear atomically; both pairs tested
// as belt-and-braces). Both exit paths drain vmcnt(0) BEFORE leaving the asm,
// so every output register is fully defined at exit (r10's crash class avoided).
// Wave-uniform sel (SGPR) tells C which slot carries the data.
__global__ __launch_bounds__(256, 1)
void reservoir_ker(const float* __restrict__ Wrec, const float* __restrict__ u,
                   float* __restrict__ pub) {
  __shared__ float st[4][256];        // wave-private raw state slice
  __shared__ float part[2][4][64];    // [t&1][wave][row]
  const int tid  = threadIdx.x;
  const int lane = tid & 63;
  const int q    = tid >> 6;
  const int g    = blockIdx.x;
  const int row  = (g << 6) + lane;          // dot row for this lane
  const int prow = (q << 4) + (lane & 15);   // publish row (within block)

  float w[256]; float wsum = 0.f;
  {
    const float* wp = Wrec + (size_t)row * 1024 + (q << 8);
#pragma unroll
    for (int j = 0; j < 64; ++j) {
      f32x4 vv = *(const f32x4*)(wp + j * 4);
      w[4 * j + 0] = vv.x; w[4 * j + 1] = vv.y; w[4 * j + 2] = vv.z; w[4 * j + 3] = vv.w;
      wsum += (vv.x + vv.y) + (vv.z + vv.w);
    }
  }
  const float wsum2 = 2.0f * wsum;

  float uval = u[(g << 6) + prow];   // u[0][publish row]

  for (int t = 0; t < 8192; ++t) {
    float accp;
    if (t == 0) {
      accp = 0.f;    // raw state = 2 everywhere: Sum(w*2) - wsum2 = 0 exactly
    } else {
      const float* p  = pub + (((size_t)(t - 1)) << 10) + (q << 8) + (lane << 2);
      const float* p2 = p + 2;
      f32x2 A0, A1, B0, B1;
      unsigned int sel;
      unsigned long long m0, m1;
      asm volatile(
        "global_load_dwordx2 %0, %7, off sc0 sc1\n\t"
        "global_load_dwordx2 %1, %8, off sc0 sc1\n\t"
        "global_load_dwordx2 %2, %7, off sc0 sc1\n\t"
        "global_load_dwordx2 %3, %8, off sc0 sc1\n\t"
        "Lchk%=:\n\t"
        "s_waitcnt vmcnt(2)\n\t"                 // oldest slot (A) landed
        "v_cmp_ne_u64 vcc, 0, %0\n\t"
        "s_mov_b64 %5, vcc\n\t"
        "v_cmp_ne_u64 vcc, 0, %1\n\t"
        "s_and_b64 %5, %5, vcc\n\t"
        "s_andn2_b64 %6, exec, %5\n\t"           // lanes NOT ready; SCC = (m!=0)
        "s_cbranch_scc0 LdoneA%=\n\t"
        "global_load_dwordx2 %0, %7, off sc0 sc1\n\t"   // reissue A
        "global_load_dwordx2 %1, %8, off sc0 sc1\n\t"
        "s_waitcnt vmcnt(2)\n\t"                 // oldest slot (B) landed
        "v_cmp_ne_u64 vcc, 0, %2\n\t"
        "s_mov_b64 %5, vcc\n\t"
        "v_cmp_ne_u64 vcc, 0, %3\n\t"
        "s_and_b64 %5, %5, vcc\n\t"
        "s_andn2_b64 %6, exec, %5\n\t"
        "s_cbranch_scc0 LdoneB%=\n\t"
        "global_load_dwordx2 %2, %7, off sc0 sc1\n\t"   // reissue B
        "global_load_dwordx2 %3, %8, off sc0 sc1\n\t"
        "s_branch Lchk%=\n\t"
        "LdoneA%=:\n\t"
        "s_waitcnt vmcnt(0)\n\t"                 // drain B before exiting asm
        "s_mov_b32 %4, 1\n\t"
        "s_branch Lend%=\n\t"
        "LdoneB%=:\n\t"
        "s_waitcnt vmcnt(0)\n\t"                 // drain A before exiting asm
        "s_mov_b32 %4, 0\n\t"
        "Lend%=:"
        : "=&v"(A0), "=&v"(A1), "=&v"(B0), "=&v"(B1),
          "=&s"(sel), "=&s"(m0), "=&s"(m1)
        : "v"(p), "v"(p2)
        : "vcc", "memory");
      f32x4 v;
      if (sel) { v.x = A0.x; v.y = A0.y; v.z = A1.x; v.w = A1.y; }
      else     { v.x = B0.x; v.y = B0.y; v.z = B1.x; v.w = B1.y; }

      *(f32x4*)&st[q][lane << 2] = v;      // st[q][i] = raw col q*256+i
      asm volatile("s_waitcnt lgkmcnt(0)" ::: "memory");  // own-wave LDS ordering
      float ac0 = 0.f, ac1 = 0.f, ac2 = 0.f, ac3 = 0.f;
      const float* sp = &st[q][0];
#pragma unroll
      for (int j = 0; j < 64; ++j) {
        f32x4 s4 = *(const f32x4*)(sp + (j << 2));
        ac0 = fmaf(w[4 * j + 0], s4.x, ac0);
        ac1 = fmaf(w[4 * j + 1], s4.y, ac1);
        ac2 = fmaf(w[4 * j + 2], s4.z, ac2);
        ac3 = fmaf(w[4 * j + 3], s4.w, ac3);
      }
      accp = ((ac0 + ac1) + (ac2 + ac3)) - wsum2;
    }
    part[t & 1][q][lane] = accp;
    // lgkm-only barrier: publish store + u prefetch stay in flight across it
    asm volatile("s_waitcnt lgkmcnt(0)" ::: "memory");
    __builtin_amdgcn_sched_barrier(0);
    __builtin_amdgcn_s_barrier();

    // every wave finalizes its own 16 rows (redundant across lane groups)
    float red = ((part[t & 1][0][prow] + part[t & 1][1][prow]) +
                 (part[t & 1][2][prow] + part[t & 1][3][prow])) + uval;
    float e  = __expf(2.0f * red);           // fast tanh: 1 - 2/(e^{2x}+1)
    float sv = 1.0f - 2.0f / (e + 1.0f);
    if (lane < 16) {
      float* pp = pub + (((size_t)t) << 10) + (g << 6) + prow;
      float val = sv + 2.0f;
      asm volatile("global_store_dword %0, %1, off sc0 sc1"
                   :: "v"(pp), "v"(val) : "memory");
    }
    if (t + 1 < 8192)
      uval = u[(((size_t)(t + 1)) << 10) + (g << 6) + prow];
  }
}

// ---------------- prediction = (pub - 2) @ W_out^T  (C=10 skinny) ----------------
__global__ __launch_bounds__(256)
void pred_ker(const float* __restrict__ hist2, const float* __restrict__ wout,
              float* __restrict__ out) {
  __shared__ float wl[10 * 1024];
  const int tid = threadIdx.x;
  for (int i = tid; i < 10240; i += 256) wl[i] = wout[i];
  __syncthreads();
  const int t = blockIdx.x * 256 + tid;
  const float* h = hist2 + (size_t)t * 1024;
  float acc[10];
#pragma unroll
  for (int c = 0; c < 10; ++c) acc[c] = 0.f;
  for (int j = 0; j < 1024; j += 4) {
    f32x4 v4 = *(const f32x4*)(h + j);
#pragma unroll
    for (int k = 0; k < 4; ++k) {
      float hv = v4[k] - 2.0f;
#pragma unroll
      for (int c = 0; c < 10; ++c) acc[c] = fmaf(hv, wl[c * 1024 + j + k], acc[c]);
    }
  }
#pragma unroll
  for (int c = 0; c < 10; ++c) out[(size_t)t * 10 + c] = acc[c];
}

extern "C" void kernel_launch(void* const* d_in, const int* in_sizes, int n_in,
                              void* d_out, int out_size, void* d_ws, size_t ws_size,
                              hipStream_t stream) {
  const float* data   = (const float*)d_in[0];
  // d_in[1] = label (int, unused)
  const float* eps    = (const float*)d_in[2];
  const float* W_enc1 = (const float*)d_in[3];
  const float* b_enc1 = (const float*)d_in[4];
  const float* W_enc2 = (const float*)d_in[5];
  const float* b_enc2 = (const float*)d_in[6];
  const float* W_mu   = (const float*)d_in[7];
  const float* b_mu   = (const float*)d_in[8];
  const float* W_lv   = (const float*)d_in[9];
  const float* b_lv   = (const float*)d_in[10];
  const float* W_dec1 = (const float*)d_in[11];
  const float* b_dec1 = (const float*)d_in[12];
  const float* W_dec2 = (const float*)d_in[13];
  const float* b_dec2 = (const float*)d_in[14];
  const float* Win    = (const float*)d_in[15];
  const float* Wrec   = (const float*)d_in[16];
  const float* W_out  = (const float*)d_in[17];

  float* out      = (float*)d_out;
  float* out_enc  = out;                       // [8192,512]
  float* out_mu   = out + (size_t)4194304;     // [8192,512]
  float* out_lv   = out + (size_t)8388608;     // [8192,512]
  float* out_z    = out + (size_t)12582912;    // [8192,512]
  float* out_dec  = out + (size_t)16777216;    // [8192,1024]
  float* out_pred = out + (size_t)25165824;    // [8192,10]

  // ws layout (aliased; peak 64 MB):
  //  phase 1: data_b @0 (16M) | wts @16M (2.1M) | ws_h @20M (8M) | encb @28M (8M) | zb @36M (8M)
  //  phase 2: ws_u f32 @0 (32M) | pub f32 @32M (32M, memset AFTER phase-1 kernels)
  char* ws = (char*)d_ws;
  u16*   data_b = (u16*)(ws);
  u16*   wts    = (u16*)(ws + 16777216);
  u16*   w1b    = wts;                 // 524288
  u16*   w2b    = wts + 524288;        // 262144
  u16*   wmub   = wts + 786432;        // 262144
  u16*   wlvb   = wts + 1048576;       // 262144
  u16*   wd1b   = wts + 1310720;       // 262144
  u16*   wd2b   = wts + 1572864;       // 524288
  u16*   ws_h   = (u16*)(ws + 20971520);       // 8 MB
  u16*   encb   = (u16*)(ws + 29360128);       // 8 MB
  u16*   zb     = (u16*)(ws + 37748736);       // 8 MB
  float* ws_u   = (float*)(ws);                // 32 MB (after phase 1)
  float* pub    = (float*)(ws + 33554432);     // 32 MB (raw state history, s+2)

  dim3 blk(256);
  // casts (f32 -> bf16)
  cast_ker<<<8192, blk, 0, stream>>>(data,   data_b, 2097152);
  cast_ker<<<512,  blk, 0, stream>>>(W_enc1, w1b,    131072);
  cast_ker<<<256,  blk, 0, stream>>>(W_enc2, w2b,    65536);
  cast_ker<<<256,  blk, 0, stream>>>(W_mu,   wmub,   65536);
  cast_ker<<<256,  blk, 0, stream>>>(W_lv,   wlvb,   65536);
  cast_ker<<<256,  blk, 0, stream>>>(W_dec1, wd1b,   65536);
  cast_ker<<<512,  blk, 0, stream>>>(W_dec2, wd2b,   131072);

  // VAE
  gemm_bt<1,1,0,1><<<dim3(64,4), blk, 0, stream>>>(data_b, w1b,  b_enc1, nullptr, ws_h,   8192, 512, 1024);
  gemm_bt<1,1,1,1><<<dim3(64,4), blk, 0, stream>>>(ws_h,   w2b,  b_enc2, out_enc, encb,   8192, 512, 512);
  gemm_bt<0,1,1,0><<<dim3(64,4), blk, 0, stream>>>(encb,   wmub, b_mu,   out_mu,  nullptr,8192, 512, 512);
  gemm_bt<0,1,1,0><<<dim3(64,4), blk, 0, stream>>>(encb,   wlvb, b_lv,   out_lv,  nullptr,8192, 512, 512);
  z_ker<<<4096, blk, 0, stream>>>(out_mu, out_lv, eps, out_z, zb, 1048576);
  gemm_bt<1,1,0,1><<<dim3(64,4), blk, 0, stream>>>(zb,     wd1b, b_dec1, nullptr, ws_h,   8192, 512, 512);
  gemm_bt<0,1,1,0><<<dim3(64,8), blk, 0, stream>>>(ws_h,   wd2b, b_dec2, out_dec, nullptr,8192, 1024, 512);

  // u = z @ Win^T in ~f32 precision (feeds 8192-step recurrence)
  gemm_split<<<dim3(64,8), blk, 0, stream>>>(out_z, Win, ws_u, 8192, 1024, 512);

  // zero pub (value-as-flag) AFTER phase-1 kernels that alias it are done,
  // before the reservoir. Required every call (pub persists across replays).
  (void)hipMemsetAsync(pub, 0, (size_t)33554432, stream);

  // reservoir + readout
  reservoir_ker<<<RG, blk, 0, stream>>>(Wrec, ws_u, pub);
  pred_ker<<<32, blk, 0, stream>>>(pub, W_out, out_pred);
}

// Round 14
// 17056.993 us; speedup vs baseline: 1.0477x; 1.0477x over previous
//
#include <hip/hip_runtime.h>

typedef unsigned short u16;
typedef __attribute__((ext_vector_type(8))) short s16x8;
typedef __attribute__((ext_vector_type(4))) float f32x4;
typedef __attribute__((ext_vector_type(4))) unsigned int u32x4;
typedef __attribute__((ext_vector_type(4))) unsigned short u16x4;

#define RG 16  // reservoir blocks

__device__ __forceinline__ float b2f(u16 u) {
  return __uint_as_float(((unsigned int)u) << 16);
}
__device__ __forceinline__ u16 f2b(float f) {   // RNE f32 -> bf16
  unsigned int x = __float_as_uint(f);
  x += 0x7fffu + ((x >> 16) & 1u);
  return (u16)(x >> 16);
}

// ---------------- f32 -> bf16 cast, 4 elems/thread ----------------
__global__ void cast_ker(const float* __restrict__ in, u16* __restrict__ out, int n4) {
  int i = blockIdx.x * blockDim.x + threadIdx.x;
  if (i >= n4) return;
  f32x4 v = ((const f32x4*)in)[i];
  u16x4 o;
  o.x = f2b(v.x); o.y = f2b(v.y); o.z = f2b(v.z); o.w = f2b(v.w);
  ((u16x4*)out)[i] = o;
}

// ---------------- GEMM: C[M,N] = act(Abf16[M,K] @ Bbf16[N,K]^T + biasf32) ----------------
template<int ACT, int BIAS, int WF32, int WB16>
__global__ __launch_bounds__(256)
void gemm_bt(const u16* __restrict__ A, const u16* __restrict__ B,
             const float* __restrict__ bias, float* __restrict__ Cf,
             u16* __restrict__ Cb, int M, int N, int K) {
  __shared__ u16 As[128 * 40];
  __shared__ u16 Bs[128 * 40];
  const int tid  = threadIdx.x;
  const int lane = tid & 63;
  const int wave = tid >> 6;
  const int wm = wave >> 1, wn = wave & 1;
  const int bm = blockIdx.x << 7;
  const int bn = blockIdx.y << 7;
  const int sr = tid >> 2;
  const int sc = (tid & 3) << 3;

  f32x4 acc[4][4];
#pragma unroll
  for (int m = 0; m < 4; ++m)
#pragma unroll
    for (int n = 0; n < 4; ++n) acc[m][n] = f32x4{0.f, 0.f, 0.f, 0.f};

  const int row0 = (wm << 6) + (lane & 15);
  const int col0 = (wn << 6) + (lane & 15);
  const int k8   = (lane >> 4) << 3;

  for (int kt = 0; kt < K; kt += 32) {
    u32x4 a0 = *(const u32x4*)(A + (size_t)(bm + sr) * K + kt + sc);
    u32x4 a1 = *(const u32x4*)(A + (size_t)(bm + sr + 64) * K + kt + sc);
    u32x4 b0 = *(const u32x4*)(B + (size_t)(bn + sr) * K + kt + sc);
    u32x4 b1 = *(const u32x4*)(B + (size_t)(bn + sr + 64) * K + kt + sc);
    __syncthreads();
    *(u32x4*)(As + sr * 40 + sc) = a0;
    *(u32x4*)(As + (sr + 64) * 40 + sc) = a1;
    *(u32x4*)(Bs + sr * 40 + sc) = b0;
    *(u32x4*)(Bs + (sr + 64) * 40 + sc) = b1;
    __syncthreads();

    s16x8 af[4], bfr[4];
#pragma unroll
    for (int m = 0; m < 4; ++m)
      af[m] = *(const s16x8*)(As + (row0 + m * 16) * 40 + k8);
#pragma unroll
    for (int n = 0; n < 4; ++n)
      bfr[n] = *(const s16x8*)(Bs + (col0 + n * 16) * 40 + k8);
#pragma unroll
    for (int m = 0; m < 4; ++m)
#pragma unroll
      for (int n = 0; n < 4; ++n)
        acc[m][n] = __builtin_amdgcn_mfma_f32_16x16x32_bf16(af[m], bfr[n], acc[m][n], 0, 0, 0);
  }

  const int crow = (wm << 6) + ((lane >> 4) << 2);
  const int ccol = (wn << 6) + (lane & 15);
#pragma unroll
  for (int m = 0; m < 4; ++m) {
#pragma unroll
    for (int n = 0; n < 4; ++n) {
      const int c = bn + ccol + n * 16;
      const float bv = BIAS ? bias[c] : 0.f;
#pragma unroll
      for (int i = 0; i < 4; ++i) {
        const int r = bm + crow + m * 16 + i;
        float v = acc[m][n][i] + bv;
        if (ACT) v = fmaxf(v, 0.f);
        if (WF32) Cf[(size_t)r * N + c] = v;
        if (WB16) Cb[(size_t)r * N + c] = f2b(v);
      }
    }
  }
}

// ---------------- split-precision GEMM: C[M,N] = Af32[M,K] @ Bf32[N,K]^T ----------------
__global__ __launch_bounds__(256)
void gemm_split(const float* __restrict__ A, const float* __restrict__ B,
                float* __restrict__ C, int M, int N, int K) {
  __shared__ u16 Ah[128 * 40];
  __shared__ u16 Al[128 * 40];
  __shared__ u16 Bh[128 * 40];
  __shared__ u16 Bl[128 * 40];
  const int tid  = threadIdx.x;
  const int lane = tid & 63;
  const int wave = tid >> 6;
  const int wm = wave >> 1, wn = wave & 1;
  const int bm = blockIdx.x << 7;
  const int bn = blockIdx.y << 7;
  const int sr = tid >> 2;
  const int sc = (tid & 3) << 3;

  f32x4 acc[4][4];
#pragma unroll
  for (int m = 0; m < 4; ++m)
#pragma unroll
    for (int n = 0; n < 4; ++n) acc[m][n] = f32x4{0.f, 0.f, 0.f, 0.f};

  const int row0 = (wm << 6) + (lane & 15);
  const int col0 = (wn << 6) + (lane & 15);
  const int k8   = (lane >> 4) << 3;

  for (int kt = 0; kt < K; kt += 32) {
    f32x4 a0 = *(const f32x4*)(A + (size_t)(bm + sr) * K + kt + sc);
    f32x4 a1 = *(const f32x4*)(A + (size_t)(bm + sr) * K + kt + sc + 4);
    f32x4 a2 = *(const f32x4*)(A + (size_t)(bm + sr + 64) * K + kt + sc);
    f32x4 a3 = *(const f32x4*)(A + (size_t)(bm + sr + 64) * K + kt + sc + 4);
    f32x4 b0 = *(const f32x4*)(B + (size_t)(bn + sr) * K + kt + sc);
    f32x4 b1 = *(const f32x4*)(B + (size_t)(bn + sr) * K + kt + sc + 4);
    f32x4 b2 = *(const f32x4*)(B + (size_t)(bn + sr + 64) * K + kt + sc);
    f32x4 b3 = *(const f32x4*)(B + (size_t)(bn + sr + 64) * K + kt + sc + 4);
    __syncthreads();
#pragma unroll
    for (int j = 0; j < 4; ++j) {
      float av, rs; u16 h;
      av = a0[j]; h = f2b(av); rs = av - b2f(h);
      Ah[sr * 40 + sc + j] = h;            Al[sr * 40 + sc + j] = f2b(rs);
      av = a1[j]; h = f2b(av); rs = av - b2f(h);
      Ah[sr * 40 + sc + 4 + j] = h;        Al[sr * 40 + sc + 4 + j] = f2b(rs);
      av = a2[j]; h = f2b(av); rs = av - b2f(h);
      Ah[(sr + 64) * 40 + sc + j] = h;     Al[(sr + 64) * 40 + sc + j] = f2b(rs);
      av = a3[j]; h = f2b(av); rs = av - b2f(h);
      Ah[(sr + 64) * 40 + sc + 4 + j] = h; Al[(sr + 64) * 40 + sc + 4 + j] = f2b(rs);
      av = b0[j]; h = f2b(av); rs = av - b2f(h);
      Bh[sr * 40 + sc + j] = h;            Bl[sr * 40 + sc + j] = f2b(rs);
      av = b1[j]; h = f2b(av); rs = av - b2f(h);
      Bh[sr * 40 + sc + 4 + j] = h;        Bl[sr * 40 + sc + 4 + j] = f2b(rs);
      av = b2[j]; h = f2b(av); rs = av - b2f(h);
      Bh[(sr + 64) * 40 + sc + j] = h;     Bl[(sr + 64) * 40 + sc + j] = f2b(rs);
      av = b3[j]; h = f2b(av); rs = av - b2f(h);
      Bh[(sr + 64) * 40 + sc + 4 + j] = h; Bl[(sr + 64) * 40 + sc + 4 + j] = f2b(rs);
    }
    __syncthreads();

    s16x8 afh[4], afl[4], bfh[4], bfl[4];
#pragma unroll
    for (int m = 0; m < 4; ++m) {
      afh[m] = *(const s16x8*)(Ah + (row0 + m * 16) * 40 + k8);
      afl[m] = *(const s16x8*)(Al + (row0 + m * 16) * 40 + k8);
    }
#pragma unroll
    for (int n = 0; n < 4; ++n) {
      bfh[n] = *(const s16x8*)(Bh + (col0 + n * 16) * 40 + k8);
      bfl[n] = *(const s16x8*)(Bl + (col0 + n * 16) * 40 + k8);
    }
#pragma unroll
    for (int m = 0; m < 4; ++m)
#pragma unroll
      for (int n = 0; n < 4; ++n) {
        acc[m][n] = __builtin_amdgcn_mfma_f32_16x16x32_bf16(afh[m], bfh[n], acc[m][n], 0, 0, 0);
        acc[m][n] = __builtin_amdgcn_mfma_f32_16x16x32_bf16(afh[m], bfl[n], acc[m][n], 0, 0, 0);
        acc[m][n] = __builtin_amdgcn_mfma_f32_16x16x32_bf16(afl[m], bfh[n], acc[m][n], 0, 0, 0);
      }
  }

  const int crow = (wm << 6) + ((lane >> 4) << 2);
  const int ccol = (wn << 6) + (lane & 15);
#pragma unroll
  for (int m = 0; m < 4; ++m)
#pragma unroll
    for (int n = 0; n < 4; ++n) {
      const int c = bn + ccol + n * 16;
#pragma unroll
      for (int i = 0; i < 4; ++i)
        C[(size_t)(bm + crow + m * 16 + i) * N + c] = acc[m][n][i];
    }
}

// ---------------- z = mu + eps * exp(0.5*log_var), f32, 4 elems/thread ----------------
__global__ void z_ker(const float* __restrict__ mu, const float* __restrict__ lv,
                      const float* __restrict__ eps, float* __restrict__ z,
                      u16* __restrict__ zb, int n4) {
  int i = blockIdx.x * blockDim.x + threadIdx.x;
  if (i >= n4) return;
  f32x4 m4 = ((const f32x4*)mu)[i];
  f32x4 l4 = ((const f32x4*)lv)[i];
  f32x4 e4 = ((const f32x4*)eps)[i];
  f32x4 o;
  o.x = m4.x + e4.x * __expf(0.5f * l4.x);
  o.y = m4.y + e4.y * __expf(0.5f * l4.y);
  o.z = m4.z + e4.z * __expf(0.5f * l4.z);
  o.w = m4.w + e4.w * __expf(0.5f * l4.w);
  ((f32x4*)z)[i] = o;
  u16x4 ob; ob.x = f2b(o.x); ob.y = f2b(o.y); ob.z = f2b(o.z); ob.w = f2b(o.w);
  ((u16x4*)zb)[i] = ob;
}

// ---------------- reservoir scan: state = tanh(Wrec @ state + u[t]) ----------------
// Best verified structure (r6/r12, 2.06 us/step — cross-CU L3 latency floor):
// 16 blocks x 4 waves. Block g owns rows [g*64,+64). Wave q polls ONLY its
// private col slice [q*256,+256) as ONE dwordx4/lane (cols 4L..4L+3);
// load+vmcnt(0) in a single asm block. pub[t][row] = s+2 in (1,3); 0 == not
// ready (value-as-flag, write-once/step); -2 bias folds into 2*rowsum(w).
// lgkm-only barrier (publish store + u prefetch stay in flight); part[]
// parity-buffered so one barrier suffices; each wave finalizes its 16 rows.
__global__ __launch_bounds__(256, 1)
void reservoir_ker(const float* __restrict__ Wrec, const float* __restrict__ u,
                   float* __restrict__ pub) {
  __shared__ float st[4][256];        // wave-private raw state slice
  __shared__ float part[2][4][64];    // [t&1][wave][row]
  const int tid  = threadIdx.x;
  const int lane = tid & 63;
  const int q    = tid >> 6;
  const int g    = blockIdx.x;
  const int row  = (g << 6) + lane;          // dot row for this lane
  const int prow = (q << 4) + (lane & 15);   // publish row (within block)

  float w[256]; float wsum = 0.f;
  {
    const float* wp = Wrec + (size_t)row * 1024 + (q << 8);
#pragma unroll
    for (int j = 0; j < 64; ++j) {
      f32x4 vv = *(const f32x4*)(wp + j * 4);
      w[4 * j + 0] = vv.x; w[4 * j + 1] = vv.y; w[4 * j + 2] = vv.z; w[4 * j + 3] = vv.w;
      wsum += (vv.x + vv.y) + (vv.z + vv.w);
    }
  }
  const float wsum2 = 2.0f * wsum;

  float uval = u[(g << 6) + prow];   // u[0][publish row]

  for (int t = 0; t < 8192; ++t) {
    float accp;
    if (t == 0) {
      accp = 0.f;    // raw state = 2 everywhere: Sum(w*2) - wsum2 = 0 exactly
    } else {
      const float* p = pub + (((size_t)(t - 1)) << 10) + (q << 8) + (lane << 2);
      f32x4 v;
      asm volatile("global_load_dwordx4 %0, %1, off sc0 sc1\n\ts_waitcnt vmcnt(0)"
                   : "=v"(v) : "v"(p) : "memory");
      while (v.x == 0.f || v.y == 0.f || v.z == 0.f || v.w == 0.f) {
        asm volatile("global_load_dwordx4 %0, %1, off sc0 sc1\n\ts_waitcnt vmcnt(0)"
                     : "=v"(v) : "v"(p) : "memory");
      }
      *(f32x4*)&st[q][lane << 2] = v;      // st[q][i] = raw col q*256+i
      asm volatile("s_waitcnt lgkmcnt(0)" ::: "memory");  // own-wave LDS ordering
      float ac0 = 0.f, ac1 = 0.f, ac2 = 0.f, ac3 = 0.f;
      const float* sp = &st[q][0];
#pragma unroll
      for (int j = 0; j < 64; ++j) {
        f32x4 s4 = *(const f32x4*)(sp + (j << 2));
        ac0 = fmaf(w[4 * j + 0], s4.x, ac0);
        ac1 = fmaf(w[4 * j + 1], s4.y, ac1);
        ac2 = fmaf(w[4 * j + 2], s4.z, ac2);
        ac3 = fmaf(w[4 * j + 3], s4.w, ac3);
      }
      accp = ((ac0 + ac1) + (ac2 + ac3)) - wsum2;
    }
    part[t & 1][q][lane] = accp;
    // lgkm-only barrier: publish store + u prefetch stay in flight across it
    asm volatile("s_waitcnt lgkmcnt(0)" ::: "memory");
    __builtin_amdgcn_sched_barrier(0);
    __builtin_amdgcn_s_barrier();

    // every wave finalizes its own 16 rows (redundant across lane groups)
    float red = ((part[t & 1][0][prow] + part[t & 1][1][prow]) +
                 (part[t & 1][2][prow] + part[t & 1][3][prow])) + uval;
    float e  = __expf(2.0f * red);           // fast tanh: 1 - 2/(e^{2x}+1)
    float sv = 1.0f - 2.0f / (e + 1.0f);
    if (lane < 16) {
      float* pp = pub + (((size_t)t) << 10) + (g << 6) + prow;
      float val = sv + 2.0f;
      asm volatile("global_store_dword %0, %1, off sc0 sc1"
                   :: "v"(pp), "v"(val) : "memory");
    }
    if (t + 1 < 8192)
      uval = u[(((size_t)(t + 1)) << 10) + (g << 6) + prow];
  }
}

// ---------------- prediction = (pub - 2) @ W_out^T  (C=10 skinny) ----------------
__global__ __launch_bounds__(256)
void pred_ker(const float* __restrict__ hist2, const float* __restrict__ wout,
              float* __restrict__ out) {
  __shared__ float wl[10 * 1024];
  const int tid = threadIdx.x;
  for (int i = tid; i < 10240; i += 256) wl[i] = wout[i];
  __syncthreads();
  const int t = blockIdx.x * 256 + tid;
  const float* h = hist2 + (size_t)t * 1024;
  float acc[10];
#pragma unroll
  for (int c = 0; c < 10; ++c) acc[c] = 0.f;
  for (int j = 0; j < 1024; j += 4) {
    f32x4 v4 = *(const f32x4*)(h + j);
#pragma unroll
    for (int k = 0; k < 4; ++k) {
      float hv = v4[k] - 2.0f;
#pragma unroll
      for (int c = 0; c < 10; ++c) acc[c] = fmaf(hv, wl[c * 1024 + j + k], acc[c]);
    }
  }
#pragma unroll
  for (int c = 0; c < 10; ++c) out[(size_t)t * 10 + c] = acc[c];
}

extern "C" void kernel_launch(void* const* d_in, const int* in_sizes, int n_in,
                              void* d_out, int out_size, void* d_ws, size_t ws_size,
                              hipStream_t stream) {
  const float* data   = (const float*)d_in[0];
  // d_in[1] = label (int, unused)
  const float* eps    = (const float*)d_in[2];
  const float* W_enc1 = (const float*)d_in[3];
  const float* b_enc1 = (const float*)d_in[4];
  const float* W_enc2 = (const float*)d_in[5];
  const float* b_enc2 = (const float*)d_in[6];
  const float* W_mu   = (const float*)d_in[7];
  const float* b_mu   = (const float*)d_in[8];
  const float* W_lv   = (const float*)d_in[9];
  const float* b_lv   = (const float*)d_in[10];
  const float* W_dec1 = (const float*)d_in[11];
  const float* b_dec1 = (const float*)d_in[12];
  const float* W_dec2 = (const float*)d_in[13];
  const float* b_dec2 = (const float*)d_in[14];
  const float* Win    = (const float*)d_in[15];
  const float* Wrec   = (const float*)d_in[16];
  const float* W_out  = (const float*)d_in[17];

  float* out      = (float*)d_out;
  float* out_enc  = out;                       // [8192,512]
  float* out_mu   = out + (size_t)4194304;     // [8192,512]
  float* out_lv   = out + (size_t)8388608;     // [8192,512]
  float* out_z    = out + (size_t)12582912;    // [8192,512]
  float* out_dec  = out + (size_t)16777216;    // [8192,1024]
  float* out_pred = out + (size_t)25165824;    // [8192,10]

  // ws layout (aliased; peak 64 MB):
  //  phase 1: data_b @0 (16M) | wts @16M (2.1M) | ws_h @20M (8M) | encb @28M (8M) | zb @36M (8M)
  //  phase 2: ws_u f32 @0 (32M) | pub f32 @32M (32M, memset AFTER phase-1 kernels)
  char* ws = (char*)d_ws;
  u16*   data_b = (u16*)(ws);
  u16*   wts    = (u16*)(ws + 16777216);
  u16*   w1b    = wts;                 // 524288
  u16*   w2b    = wts + 524288;        // 262144
  u16*   wmub   = wts + 786432;        // 262144
  u16*   wlvb   = wts + 1048576;       // 262144
  u16*   wd1b   = wts + 1310720;       // 262144
  u16*   wd2b   = wts + 1572864;       // 524288
  u16*   ws_h   = (u16*)(ws + 20971520);       // 8 MB
  u16*   encb   = (u16*)(ws + 29360128);       // 8 MB
  u16*   zb     = (u16*)(ws + 37748736);       // 8 MB
  float* ws_u   = (float*)(ws);                // 32 MB (after phase 1)
  float* pub    = (float*)(ws + 33554432);     // 32 MB (raw state history, s+2)

  dim3 blk(256);
  // casts (f32 -> bf16)
  cast_ker<<<8192, blk, 0, stream>>>(data,   data_b, 2097152);
  cast_ker<<<512,  blk, 0, stream>>>(W_enc1, w1b,    131072);
  cast_ker<<<256,  blk, 0, stream>>>(W_enc2, w2b,    65536);
  cast_ker<<<256,  blk, 0, stream>>>(W_mu,   wmub,   65536);
  cast_ker<<<256,  blk, 0, stream>>>(W_lv,   wlvb,   65536);
  cast_ker<<<256,  blk, 0, stream>>>(W_dec1, wd1b,   65536);
  cast_ker<<<512,  blk, 0, stream>>>(W_dec2, wd2b,   131072);

  // VAE
  gemm_bt<1,1,0,1><<<dim3(64,4), blk, 0, stream>>>(data_b, w1b,  b_enc1, nullptr, ws_h,   8192, 512, 1024);
  gemm_bt<1,1,1,1><<<dim3(64,4), blk, 0, stream>>>(ws_h,   w2b,  b_enc2, out_enc, encb,   8192, 512, 512);
  gemm_bt<0,1,1,0><<<dim3(64,4), blk, 0, stream>>>(encb,   wmub, b_mu,   out_mu,  nullptr,8192, 512, 512);
  gemm_bt<0,1,1,0><<<dim3(64,4), blk, 0, stream>>>(encb,   wlvb, b_lv,   out_lv,  nullptr,8192, 512, 512);
  z_ker<<<4096, blk, 0, stream>>>(out_mu, out_lv, eps, out_z, zb, 1048576);
  gemm_bt<1,1,0,1><<<dim3(64,4), blk, 0, stream>>>(zb,     wd1b, b_dec1, nullptr, ws_h,   8192, 512, 512);
  gemm_bt<0,1,1,0><<<dim3(64,8), blk, 0, stream>>>(ws_h,   wd2b, b_dec2, out_dec, nullptr,8192, 1024, 512);

  // u = z @ Win^T in ~f32 precision (feeds 8192-step recurrence)
  gemm_split<<<dim3(64,8), blk, 0, stream>>>(out_z, Win, ws_u, 8192, 1024, 512);

  // zero pub (value-as-flag) AFTER phase-1 kernels that alias it are done,
  // before the reservoir. Required every call (pub persists across replays).
  (void)hipMemsetAsync(pub, 0, (size_t)33554432, stream);

  // reservoir + readout
  reservoir_ker<<<RG, blk, 0, stream>>>(Wrec, ws_u, pub);
  pred_ker<<<32, blk, 0, stream>>>(pub, W_out, out_pred);
}